// Round 1
// baseline (57.045 us; speedup 1.0000x reference)
//
#include <hip/hip_runtime.h>
#include <math.h>

#define TWO_PI 6.28318530717958647692f

// One wave (64 lanes) per (b,n) item; lane k handles mixture component k (K=64).
// Block of 8 waves covers all N items of one batch index b; ldj reduced
// deterministically in LDS (no atomics, no workspace).
__global__ __launch_bounds__(512, 2)
void mobius_fwd(const float* __restrict__ rot,
                const float* __restrict__ cond,
                const void* __restrict__ perm,
                float* __restrict__ out,
                int B, int N)
{
    const int b     = blockIdx.x;
    const int wave  = threadIdx.x >> 6;
    const int lane  = threadIdx.x & 63;
    const int nwav  = blockDim.x >> 6;

    // permute: harness may deliver int32 or int64; detect a valid int32 permutation.
    const int* pi = (const int*)perm;
    int p0 = pi[0], p1 = pi[1], p2 = pi[2];
    bool ok = ((unsigned)p0 < 3u) && ((unsigned)p1 < 3u) && ((unsigned)p2 < 3u)
              && (p0 != p1) && (p0 != p2) && (p1 != p2);
    if (!ok) {
        const long long* pl = (const long long*)perm;
        p0 = (int)pl[0]; p1 = (int)pl[1]; p2 = (int)pl[2];
    }

    __shared__ float s_ldj[64];

    for (int n = wave; n < N; n += nwav) {
        const int item = b * N + n;
        const float* R = rot + (size_t)item * 9;

        // x = column p0, y = column p1 (raw, unnormalized)
        float x0 = R[0 * 3 + p0], x1 = R[1 * 3 + p0], x2 = R[2 * 3 + p0];
        float y0 = R[0 * 3 + p1], y1 = R[1 * 3 + p1], y2 = R[2 * 3 + p1];

        // r = -x / ||x||
        float inv_xn = rsqrtf(x0 * x0 + x1 * x1 + x2 * x2);
        float r0 = -x0 * inv_xn, r1 = -x1 * inv_xn, r2 = -x2 * inv_xn;

        // v = normalize(cross(y, r))
        float v0 = y1 * r2 - y2 * r1;
        float v1 = y2 * r0 - y0 * r2;
        float v2 = y0 * r1 - y1 * r0;
        float inv_vn = rsqrtf(v0 * v0 + v1 * v1 + v2 * v2);
        v0 *= inv_vn; v1 *= inv_vn; v2 *= inv_vn;

        // per-lane mixture component k = lane
        const float* C = cond + (size_t)item * 256;
        float pw = C[lane];
        float w0 = C[64 + 3 * lane + 0];
        float w1 = C[64 + 3 * lane + 1];
        float w2 = C[64 + 3 * lane + 2];

        // proj = I - y y^T (raw y)
        float yd = y0 * w0 + y1 * w1 + y2 * w2;
        w0 -= y0 * yd; w1 -= y1 * yd; w2 -= y2 * yd;

        // shrink: w *= 0.7/(1+||w||)
        float wn = sqrtf(w0 * w0 + w1 * w1 + w2 * w2);
        float s = 0.7f / (1.0f + wn);
        w0 *= s; w1 *= s; w2 *= s;
        float wn2 = w0 * w0 + w1 * w1 + w2 * w2;

        // zw = x - w ; c = (1-||w||^2)/||zw||^2
        float zw0 = x0 - w0, zw1 = x1 - w1, zw2 = x2 - w2;
        float zwn2 = zw0 * zw0 + zw1 * zw1 + zw2 * zw2;
        float c = (1.0f - wn2) / zwn2;

        // h = c*zw - w ; angle
        float h0 = c * zw0 - w0, h1 = c * zw1 - w1, h2 = c * zw2 - w2;
        float hv = h0 * v0 + h1 * v1 + h2 * v2;
        float hr = h0 * r0 + h1 * r1 + h2 * r2;
        float rad = atan2f(hv, hr);
        float ang = (rad >= 0.0f) ? rad : rad + TWO_PI;

        // softplus weight (stable)
        float p = fmaxf(pw, 0.0f) + log1pf(expf(-fabsf(pw)));

        // NOTE: ||dh_dtheta_k|| == c_k exactly: dh_dz is c*(reflection), and
        // dz_dtheta = -sin(th)*r + cos(th)*v has unit norm (r perp v, unit).
        float a = p * ang;
        float d = p * c;

        // wave reduction of (p, a, d)
        #pragma unroll
        for (int off = 32; off >= 1; off >>= 1) {
            p += __shfl_xor(p, off, 64);
            a += __shfl_xor(a, off, 64);
            d += __shfl_xor(d, off, 64);
        }

        float angT = a / p;
        float dtx  = d / p;
        float ldj  = logf(dtx);

        if (lane == 0) {
            float sa, ca;
            sincosf(angT, &sa, &ca);
            float t0 = r0 * ca + v0 * sa;
            float t1 = r1 * ca + v1 * sa;
            float t2 = r2 * ca + v2 * sa;

            float u0, u1, u2;
            int dd = p1 - p0;
            if (dd == 1 || dd == -2) {  // tz = cross(tx, y)
                u0 = t1 * y2 - t2 * y1;
                u1 = t2 * y0 - t0 * y2;
                u2 = t0 * y1 - t1 * y0;
            } else {                    // tz = cross(y, tx)
                u0 = y1 * t2 - y2 * t1;
                u1 = y2 * t0 - y0 * t2;
                u2 = y0 * t1 - y1 * t0;
            }
            float iun = rsqrtf(u0 * u0 + u1 * u1 + u2 * u2);
            u0 *= iun; u1 *= iun; u2 *= iun;

            float* T = out + (size_t)item * 9;
            T[0 * 3 + p0] = t0; T[1 * 3 + p0] = t1; T[2 * 3 + p0] = t2;
            T[0 * 3 + p1] = y0; T[1 * 3 + p1] = y1; T[2 * 3 + p1] = y2;
            T[0 * 3 + p2] = u0; T[1 * 3 + p2] = u1; T[2 * 3 + p2] = u2;

            s_ldj[n] = ldj;
        }
    }

    __syncthreads();
    if (threadIdx.x == 0) {
        float acc = 0.0f;
        for (int n = 0; n < N; ++n) acc += s_ldj[n];
        out[(size_t)B * N * 9 + b] = acc;
    }
}

extern "C" void kernel_launch(void* const* d_in, const int* in_sizes, int n_in,
                              void* d_out, int out_size, void* d_ws, size_t ws_size,
                              hipStream_t stream) {
    const float* rot  = (const float*)d_in[0];
    const float* cond = (const float*)d_in[1];
    const void*  perm = d_in[2];
    float* out = (float*)d_out;

    int items = in_sizes[0] / 9;           // B*N
    int B = out_size - items * 9;          // out = items*9 trot + B ldj
    int N = items / B;

    mobius_fwd<<<dim3(B), dim3(512), 0, stream>>>(rot, cond, perm, out, B, N);
}

// Round 2
// 37.678 us; speedup vs baseline: 1.5140x; 1.5140x over previous
//
#include <hip/hip_runtime.h>
#include <math.h>

#define PI_F    3.14159265358979323846f
#define TWO_PI  6.28318530717958647692f
#define HALF_PI 1.57079632679489661923f

__device__ __forceinline__ float frcp(float x)  { return __builtin_amdgcn_rcpf(x); }
__device__ __forceinline__ float frsq(float x)  { return __builtin_amdgcn_rsqf(x); }
__device__ __forceinline__ float fsqrt(float x) { return __builtin_amdgcn_sqrtf(x); }

// atan2(y,x) mapped to [0, 2pi). A&S 4.4.49 poly, |err| <= 1e-5 rad.
__device__ __forceinline__ float fast_atan2_2pi(float y, float x) {
    float ax = fabsf(x), ay = fabsf(y);
    float mx = fmaxf(ax, ay), mn = fminf(ax, ay);
    float a  = (mx > 0.0f) ? mn * frcp(mx) : 0.0f;
    float s  = a * a;
    float r  = fmaf(s, fmaf(s, fmaf(s, fmaf(s, 0.0208351f, -0.085133f),
                                    0.180141f), -0.3302995f), 0.9998660f) * a;
    if (ay > ax) r = HALF_PI - r;
    if (x < 0.0f) r = PI_F - r;
    return (y < 0.0f) ? (TWO_PI - r) : r;
}

// One wave (64 lanes) per (b,n) item; lane k = mixture component k (K=64).
// Block of 7 waves covers N=21 items of one batch index b in exactly 3
// passes per wave (perfect balance). ldj reduced deterministically in LDS.
__global__ __launch_bounds__(448)
void mobius_fwd(const float* __restrict__ rot,
                const float* __restrict__ cond,
                const void* __restrict__ perm,
                float* __restrict__ out,
                int B, int N)
{
    const int b    = blockIdx.x;
    const int wave = threadIdx.x >> 6;
    const int lane = threadIdx.x & 63;
    const int nwav = blockDim.x >> 6;

    // permute: accept int32 or int64 delivery.
    const int* pi = (const int*)perm;
    int p0 = pi[0], p1 = pi[1], p2 = pi[2];
    bool ok = ((unsigned)p0 < 3u) && ((unsigned)p1 < 3u) && ((unsigned)p2 < 3u)
              && (p0 != p1) && (p0 != p2) && (p1 != p2);
    if (!ok) {
        const long long* pl = (const long long*)perm;
        p0 = (int)pl[0]; p1 = (int)pl[1]; p2 = (int)pl[2];
    }

    __shared__ float s_ldj[32];

    for (int n = wave; n < N; n += nwav) {
        const int item = b * N + n;
        const float* R = rot + (size_t)item * 9;

        float x0 = R[0 * 3 + p0], x1 = R[1 * 3 + p0], x2 = R[2 * 3 + p0];
        float y0 = R[0 * 3 + p1], y1 = R[1 * 3 + p1], y2 = R[2 * 3 + p1];

        // r = -x/||x||
        float inv_xn = frsq(x0 * x0 + x1 * x1 + x2 * x2);
        float r0 = -x0 * inv_xn, r1 = -x1 * inv_xn, r2 = -x2 * inv_xn;

        // v = normalize(cross(y, r))
        float v0 = y1 * r2 - y2 * r1;
        float v1 = y2 * r0 - y0 * r2;
        float v2 = y0 * r1 - y1 * r0;
        float inv_vn = frsq(v0 * v0 + v1 * v1 + v2 * v2);
        v0 *= inv_vn; v1 *= inv_vn; v2 *= inv_vn;

        // lane k component
        const float* C = cond + (size_t)item * 256;
        float pw = C[lane];
        float w0 = C[64 + 3 * lane + 0];
        float w1 = C[64 + 3 * lane + 1];
        float w2 = C[64 + 3 * lane + 2];

        // proj = I - y y^T (raw y)
        float yd = y0 * w0 + y1 * w1 + y2 * w2;
        w0 -= y0 * yd; w1 -= y1 * yd; w2 -= y2 * yd;

        // shrink: w *= 0.7/(1+||w||)
        float q  = w0 * w0 + w1 * w1 + w2 * w2;
        float sc = 0.7f * frcp(1.0f + fsqrt(q));
        w0 *= sc; w1 *= sc; w2 *= sc;
        float wn2 = w0 * w0 + w1 * w1 + w2 * w2;

        // zw = x - w ; c = (1-||w||^2)/||zw||^2  (== ||dh_dtheta_k|| exactly)
        float zw0 = x0 - w0, zw1 = x1 - w1, zw2 = x2 - w2;
        float zwn2 = zw0 * zw0 + zw1 * zw1 + zw2 * zw2;
        float c = (1.0f - wn2) * frcp(zwn2);

        // h = c*zw - w ; angle in (r,v) basis
        float h0 = c * zw0 - w0, h1 = c * zw1 - w1, h2 = c * zw2 - w2;
        float hv = h0 * v0 + h1 * v1 + h2 * v2;
        float hr = h0 * r0 + h1 * r1 + h2 * r2;
        float ang = fast_atan2_2pi(hv, hr);

        // softplus (stable, native exp/log)
        float t = __expf(-fabsf(pw));
        float p = fmaxf(pw, 0.0f) + __logf(1.0f + t);

        float a = p * ang;
        float d = p * c;

        #pragma unroll
        for (int off = 32; off >= 1; off >>= 1) {
            p += __shfl_xor(p, off, 64);
            a += __shfl_xor(a, off, 64);
            d += __shfl_xor(d, off, 64);
        }

        float ip   = frcp(p);
        float angT = a * ip;
        float ldj  = __logf(d * ip);

        if (lane == 0) {
            float sa, ca;
            __sincosf(angT, &sa, &ca);
            float t0 = r0 * ca + v0 * sa;
            float t1 = r1 * ca + v1 * sa;
            float t2 = r2 * ca + v2 * sa;

            float u0, u1, u2;
            int dd = p1 - p0;
            if (dd == 1 || dd == -2) {  // tz = cross(tx, y)
                u0 = t1 * y2 - t2 * y1;
                u1 = t2 * y0 - t0 * y2;
                u2 = t0 * y1 - t1 * y0;
            } else {                    // tz = cross(y, tx)
                u0 = y1 * t2 - y2 * t1;
                u1 = y2 * t0 - y0 * t2;
                u2 = y0 * t1 - y1 * t0;
            }
            float iun = frsq(u0 * u0 + u1 * u1 + u2 * u2);
            u0 *= iun; u1 *= iun; u2 *= iun;

            float* T = out + (size_t)item * 9;
            T[0 * 3 + p0] = t0; T[1 * 3 + p0] = t1; T[2 * 3 + p0] = t2;
            T[0 * 3 + p1] = y0; T[1 * 3 + p1] = y1; T[2 * 3 + p1] = y2;
            T[0 * 3 + p2] = u0; T[1 * 3 + p2] = u1; T[2 * 3 + p2] = u2;

            s_ldj[n] = ldj;
        }
    }

    __syncthreads();
    if (threadIdx.x == 0) {
        float acc = 0.0f;
        for (int n = 0; n < N; ++n) acc += s_ldj[n];
        out[(size_t)B * N * 9 + b] = acc;
    }
}

extern "C" void kernel_launch(void* const* d_in, const int* in_sizes, int n_in,
                              void* d_out, int out_size, void* d_ws, size_t ws_size,
                              hipStream_t stream) {
    const float* rot  = (const float*)d_in[0];
    const float* cond = (const float*)d_in[1];
    const void*  perm = d_in[2];
    float* out = (float*)d_out;

    int items = in_sizes[0] / 9;           // B*N
    int B = out_size - items * 9;          // out = items*9 trot + B ldj
    int N = items / B;

    mobius_fwd<<<dim3(B), dim3(448), 0, stream>>>(rot, cond, perm, out, B, N);
}

// Round 3
// 30.891 us; speedup vs baseline: 1.8467x; 1.2197x over previous
//
#include <hip/hip_runtime.h>
#include <math.h>

#define PI_F    3.14159265358979323846f
#define TWO_PI  6.28318530717958647692f
#define HALF_PI 1.57079632679489661923f

__device__ __forceinline__ float frcp(float x)  { return __builtin_amdgcn_rcpf(x); }
__device__ __forceinline__ float frsq(float x)  { return __builtin_amdgcn_rsqf(x); }
__device__ __forceinline__ float fsqrt(float x) { return __builtin_amdgcn_sqrtf(x); }

// atan2(y,x) mapped to [0, 2pi). A&S 4.4.49 poly, |err| <= 1e-5 rad.
__device__ __forceinline__ float fast_atan2_2pi(float y, float x) {
    float ax = fabsf(x), ay = fabsf(y);
    float mx = fmaxf(ax, ay), mn = fminf(ax, ay);
    float a  = (mx > 0.0f) ? mn * frcp(mx) : 0.0f;
    float s  = a * a;
    float r  = fmaf(s, fmaf(s, fmaf(s, fmaf(s, 0.0208351f, -0.085133f),
                                    0.180141f), -0.3302995f), 0.9998660f) * a;
    if (ay > ax) r = HALF_PI - r;
    if (x < 0.0f) r = PI_F - r;
    return (y < 0.0f) ? (TWO_PI - r) : r;
}

// Two items per wave: lanes 0-31 = item A, lanes 32-63 = item B.
// Lane j (within its 32-lane half) handles mixture components 2j, 2j+1.
// Block of 7 waves covers TWO batch rows (42 items = 21 pairs) in exactly
// 3 iterations per wave. ldj reduced deterministically in LDS.
__global__ __launch_bounds__(448)
void mobius_fwd(const float* __restrict__ rot,
                const float* __restrict__ cond,
                const void* __restrict__ perm,
                float* __restrict__ out,
                int B, int N)
{
    const int wave = threadIdx.x >> 6;
    const int lane = threadIdx.x & 63;
    const int half = lane >> 5;
    const int j    = lane & 31;
    const int nwav = blockDim.x >> 6;

    const int b0     = blockIdx.x * 2;
    const int nb     = min(2, B - b0);
    const int nit    = N * nb;
    const int npairs = (nit + 1) >> 1;

    // permute: accept int32 or int64 delivery.
    const int* pi = (const int*)perm;
    int p0 = pi[0], p1 = pi[1], p2 = pi[2];
    bool pok = ((unsigned)p0 < 3u) && ((unsigned)p1 < 3u) && ((unsigned)p2 < 3u)
               && (p0 != p1) && (p0 != p2) && (p1 != p2);
    if (!pok) {
        const long long* pl = (const long long*)perm;
        p0 = (int)pl[0]; p1 = (int)pl[1]; p2 = (int)pl[2];
    }

    __shared__ float s_ldj[64];

    const size_t base_item = (size_t)b0 * N;

    for (int pidx = wave; pidx < npairs; pidx += nwav) {
        const int  i0    = 2 * pidx + half;   // group-local item index
        const bool valid = (i0 < nit);
        const int  iv    = valid ? i0 : 0;    // clamp for safe addressing
        const size_t item = base_item + iv;

        const float* R = rot + item * 9;
        float x0 = R[p0], x1 = R[3 + p0], x2 = R[6 + p0];
        float y0 = R[p1], y1 = R[3 + p1], y2 = R[6 + p1];

        // r = -x/||x||
        float inv_xn = frsq(x0 * x0 + x1 * x1 + x2 * x2);
        float r0 = -x0 * inv_xn, r1 = -x1 * inv_xn, r2 = -x2 * inv_xn;

        // v = normalize(cross(y, r))
        float v0 = y1 * r2 - y2 * r1;
        float v1 = y2 * r0 - y0 * r2;
        float v2 = y0 * r1 - y1 * r0;
        float inv_vn = frsq(v0 * v0 + v1 * v1 + v2 * v2);
        v0 *= inv_vn; v1 *= inv_vn; v2 *= inv_vn;

        // components 2j and 2j+1: 8 floats via aligned float2 loads
        const float* C = cond + item * 256;
        float2 pw2 = *(const float2*)(C + 2 * j);
        float2 wa  = *(const float2*)(C + 64 + 6 * j);
        float2 wx  = *(const float2*)(C + 66 + 6 * j);
        float2 wb  = *(const float2*)(C + 68 + 6 * j);

        float pp = 0.0f, pa = 0.0f, pd = 0.0f;

        auto docomp = [&](float pw, float w0, float w1, float w2) {
            // proj = I - y y^T (raw y)
            float yd = y0 * w0 + y1 * w1 + y2 * w2;
            w0 -= y0 * yd; w1 -= y1 * yd; w2 -= y2 * yd;
            // shrink: w *= 0.7/(1+||w||)
            float q  = w0 * w0 + w1 * w1 + w2 * w2;
            float sc = 0.7f * frcp(1.0f + fsqrt(q));
            w0 *= sc; w1 *= sc; w2 *= sc;
            float wn2 = w0 * w0 + w1 * w1 + w2 * w2;
            // zw = x - w ; c = (1-||w||^2)/||zw||^2  (== ||dh_dtheta|| exactly)
            float zw0 = x0 - w0, zw1 = x1 - w1, zw2 = x2 - w2;
            float zwn2 = zw0 * zw0 + zw1 * zw1 + zw2 * zw2;
            float c = (1.0f - wn2) * frcp(zwn2);
            // h = c*zw - w ; angle in (r,v) basis
            float h0 = c * zw0 - w0, h1 = c * zw1 - w1, h2 = c * zw2 - w2;
            float hv = h0 * v0 + h1 * v1 + h2 * v2;
            float hr = h0 * r0 + h1 * r1 + h2 * r2;
            float ang = fast_atan2_2pi(hv, hr);
            // softplus (stable, native exp/log)
            float t = __expf(-fabsf(pw));
            float p = fmaxf(pw, 0.0f) + __logf(1.0f + t);
            pp += p; pa += p * ang; pd += p * c;
        };
        docomp(pw2.x, wa.x, wa.y, wx.x);
        docomp(pw2.y, wx.y, wb.x, wb.y);

        // butterfly within each 32-lane half (3 sums)
        #pragma unroll
        for (int off = 16; off >= 1; off >>= 1) {
            pp += __shfl_xor(pp, off, 64);
            pa += __shfl_xor(pa, off, 64);
            pd += __shfl_xor(pd, off, 64);
        }

        if (j == 0 && valid) {
            float ip   = frcp(pp);
            float angT = pa * ip;
            float ldj  = __logf(pd * ip);

            float sa, ca;
            __sincosf(angT, &sa, &ca);
            float t0 = r0 * ca + v0 * sa;
            float t1 = r1 * ca + v1 * sa;
            float t2 = r2 * ca + v2 * sa;

            float u0, u1, u2;
            int dd = p1 - p0;
            if (dd == 1 || dd == -2) {  // tz = cross(tx, y)
                u0 = t1 * y2 - t2 * y1;
                u1 = t2 * y0 - t0 * y2;
                u2 = t0 * y1 - t1 * y0;
            } else {                    // tz = cross(y, tx)
                u0 = y1 * t2 - y2 * t1;
                u1 = y2 * t0 - y0 * t2;
                u2 = y0 * t1 - y1 * t0;
            }
            float iun = frsq(u0 * u0 + u1 * u1 + u2 * u2);
            u0 *= iun; u1 *= iun; u2 *= iun;

            float* T = out + item * 9;
            T[p0] = t0; T[3 + p0] = t1; T[6 + p0] = t2;
            T[p1] = y0; T[3 + p1] = y1; T[6 + p1] = y2;
            T[p2] = u0; T[3 + p2] = u1; T[6 + p2] = u2;

            s_ldj[i0] = ldj;
        }
    }

    __syncthreads();
    if (threadIdx.x < nb) {
        float acc = 0.0f;
        for (int n = 0; n < N; ++n) acc += s_ldj[threadIdx.x * N + n];
        out[(size_t)B * N * 9 + b0 + threadIdx.x] = acc;
    }
}

extern "C" void kernel_launch(void* const* d_in, const int* in_sizes, int n_in,
                              void* d_out, int out_size, void* d_ws, size_t ws_size,
                              hipStream_t stream) {
    const float* rot  = (const float*)d_in[0];
    const float* cond = (const float*)d_in[1];
    const void*  perm = d_in[2];
    float* out = (float*)d_out;

    int items = in_sizes[0] / 9;           // B*N
    int B = out_size - items * 9;          // out = items*9 trot + B ldj
    int N = items / B;

    int grid = (B + 1) / 2;
    mobius_fwd<<<dim3(grid), dim3(448), 0, stream>>>(rot, cond, perm, out, B, N);
}

// Round 4
// 25.373 us; speedup vs baseline: 2.2483x; 1.2175x over previous
//
#include <hip/hip_runtime.h>
#include <math.h>

#define PI_F    3.14159265358979323846f
#define TWO_PI  6.28318530717958647692f
#define HALF_PI 1.57079632679489661923f

__device__ __forceinline__ float frcp(float x)  { return __builtin_amdgcn_rcpf(x); }
__device__ __forceinline__ float frsq(float x)  { return __builtin_amdgcn_rsqf(x); }
__device__ __forceinline__ float fsqrt(float x) { return __builtin_amdgcn_sqrtf(x); }

// atan2(y,x) mapped to [0, 2pi). A&S 4.4.49 poly, |err| <= 1e-5 rad.
__device__ __forceinline__ float fast_atan2_2pi(float y, float x) {
    float ax = fabsf(x), ay = fabsf(y);
    float mx = fmaxf(ax, ay), mn = fminf(ax, ay);
    float a  = (mx > 0.0f) ? mn * frcp(mx) : 0.0f;
    float s  = a * a;
    float r  = fmaf(s, fmaf(s, fmaf(s, fmaf(s, 0.0208351f, -0.085133f),
                                    0.180141f), -0.3302995f), 0.9998660f) * a;
    if (ay > ax) r = HALF_PI - r;
    if (x < 0.0f) r = PI_F - r;
    return (y < 0.0f) ? (TWO_PI - r) : r;
}

// Four items per wave: 16-lane group per item; lane j (0..15) handles
// mixture components 4j..4j+3 (K=64). Block of 7 waves covers FOUR batch
// rows (84 items = 21 quads) in exactly 3 iterations per wave.
// ldj reduced deterministically in LDS.
__global__ __launch_bounds__(448)
void mobius_fwd(const float* __restrict__ rot,
                const float* __restrict__ cond,
                const void* __restrict__ perm,
                float* __restrict__ out,
                int B, int N)
{
    const int wave = threadIdx.x >> 6;
    const int lane = threadIdx.x & 63;
    const int sub  = lane >> 4;      // which of 4 items in the wave
    const int j    = lane & 15;      // 16-lane slot within item
    const int nwav = blockDim.x >> 6;

    const int b0     = blockIdx.x * 4;
    const int nb     = min(4, B - b0);
    const int nit    = N * nb;              // 84 when full
    const int nquads = (nit + 3) >> 2;      // 21 when full

    // permute: accept int32 or int64 delivery.
    const int* pi = (const int*)perm;
    int p0 = pi[0], p1 = pi[1], p2 = pi[2];
    bool pok = ((unsigned)p0 < 3u) && ((unsigned)p1 < 3u) && ((unsigned)p2 < 3u)
               && (p0 != p1) && (p0 != p2) && (p1 != p2);
    if (!pok) {
        const long long* pl = (const long long*)perm;
        p0 = (int)pl[0]; p1 = (int)pl[1]; p2 = (int)pl[2];
    }

    __shared__ float s_ldj[256];   // holds 4*N item ldjs (N<=64)

    const size_t base_item = (size_t)b0 * N;

    for (int q = wave; q < nquads; q += nwav) {
        const int  i0    = 4 * q + sub;     // group-local item index
        const bool valid = (i0 < nit);
        const int  iv    = valid ? i0 : 0;
        const size_t item = base_item + iv;

        const float* R = rot + item * 9;
        float x0 = R[p0], x1 = R[3 + p0], x2 = R[6 + p0];
        float y0 = R[p1], y1 = R[3 + p1], y2 = R[6 + p1];

        // r = -x/||x||
        float inv_xn = frsq(x0 * x0 + x1 * x1 + x2 * x2);
        float r0 = -x0 * inv_xn, r1 = -x1 * inv_xn, r2 = -x2 * inv_xn;

        // v = normalize(cross(y, r))
        float v0 = y1 * r2 - y2 * r1;
        float v1 = y2 * r0 - y0 * r2;
        float v2 = y0 * r1 - y1 * r0;
        float inv_vn = frsq(v0 * v0 + v1 * v1 + v2 * v2);
        v0 *= inv_vn; v1 *= inv_vn; v2 *= inv_vn;

        // components 4j..4j+3: 16 floats via aligned float4 loads
        const float* C = cond + item * 256;
        float4 pw4 = *(const float4*)(C + 4 * j);
        float4 fa  = *(const float4*)(C + 64 + 12 * j);
        float4 fb  = *(const float4*)(C + 68 + 12 * j);
        float4 fc  = *(const float4*)(C + 72 + 12 * j);

        float pp = 0.0f, pa = 0.0f, pd = 0.0f;

        auto docomp = [&](float pw, float w0, float w1, float w2) {
            // proj = I - y y^T (raw y)
            float yd = y0 * w0 + y1 * w1 + y2 * w2;
            w0 -= y0 * yd; w1 -= y1 * yd; w2 -= y2 * yd;
            // shrink: w *= 0.7/(1+||w||)
            float qn  = w0 * w0 + w1 * w1 + w2 * w2;
            float sc = 0.7f * frcp(1.0f + fsqrt(qn));
            w0 *= sc; w1 *= sc; w2 *= sc;
            float wn2 = w0 * w0 + w1 * w1 + w2 * w2;
            // zw = x - w ; c = (1-||w||^2)/||zw||^2  (== ||dh_dtheta|| exactly)
            float zw0 = x0 - w0, zw1 = x1 - w1, zw2 = x2 - w2;
            float zwn2 = zw0 * zw0 + zw1 * zw1 + zw2 * zw2;
            float c = (1.0f - wn2) * frcp(zwn2);
            // h = c*zw - w ; angle in (r,v) basis
            float h0 = c * zw0 - w0, h1 = c * zw1 - w1, h2 = c * zw2 - w2;
            float hv = h0 * v0 + h1 * v1 + h2 * v2;
            float hr = h0 * r0 + h1 * r1 + h2 * r2;
            float ang = fast_atan2_2pi(hv, hr);
            // softplus (stable, native exp/log)
            float t = __expf(-fabsf(pw));
            float p = fmaxf(pw, 0.0f) + __logf(1.0f + t);
            pp += p; pa += p * ang; pd += p * c;
        };
        docomp(pw4.x, fa.x, fa.y, fa.z);
        docomp(pw4.y, fa.w, fb.x, fb.y);
        docomp(pw4.z, fb.z, fb.w, fc.x);
        docomp(pw4.w, fc.y, fc.z, fc.w);

        // butterfly within each 16-lane group (3 sums)
        #pragma unroll
        for (int off = 8; off >= 1; off >>= 1) {
            pp += __shfl_xor(pp, off, 64);
            pa += __shfl_xor(pa, off, 64);
            pd += __shfl_xor(pd, off, 64);
        }

        if (j == 0 && valid) {
            float ip   = frcp(pp);
            float angT = pa * ip;
            float ldj  = __logf(pd * ip);

            float sa, ca;
            __sincosf(angT, &sa, &ca);
            float t0 = r0 * ca + v0 * sa;
            float t1 = r1 * ca + v1 * sa;
            float t2 = r2 * ca + v2 * sa;

            float u0, u1, u2;
            int dd = p1 - p0;
            if (dd == 1 || dd == -2) {  // tz = cross(tx, y)
                u0 = t1 * y2 - t2 * y1;
                u1 = t2 * y0 - t0 * y2;
                u2 = t0 * y1 - t1 * y0;
            } else {                    // tz = cross(y, tx)
                u0 = y1 * t2 - y2 * t1;
                u1 = y2 * t0 - y0 * t2;
                u2 = y0 * t1 - y1 * t0;
            }
            float iun = frsq(u0 * u0 + u1 * u1 + u2 * u2);
            u0 *= iun; u1 *= iun; u2 *= iun;

            float* T = out + item * 9;
            T[p0] = t0; T[3 + p0] = t1; T[6 + p0] = t2;
            T[p1] = y0; T[3 + p1] = y1; T[6 + p1] = y2;
            T[p2] = u0; T[3 + p2] = u1; T[6 + p2] = u2;

            s_ldj[i0] = ldj;
        }
    }

    __syncthreads();
    if (threadIdx.x < nb) {
        float acc = 0.0f;
        for (int n = 0; n < N; ++n) acc += s_ldj[threadIdx.x * N + n];
        out[(size_t)B * N * 9 + b0 + threadIdx.x] = acc;
    }
}

extern "C" void kernel_launch(void* const* d_in, const int* in_sizes, int n_in,
                              void* d_out, int out_size, void* d_ws, size_t ws_size,
                              hipStream_t stream) {
    const float* rot  = (const float*)d_in[0];
    const float* cond = (const float*)d_in[1];
    const void*  perm = d_in[2];
    float* out = (float*)d_out;

    int items = in_sizes[0] / 9;           // B*N
    int B = out_size - items * 9;          // out = items*9 trot + B ldj
    int N = items / B;

    int grid = (B + 3) / 4;
    mobius_fwd<<<dim3(grid), dim3(448), 0, stream>>>(rot, cond, perm, out, B, N);
}